// Round 10
// baseline (1401.161 us; speedup 1.0000x reference)
//
#include <hip/hip_runtime.h>

// GATClassifier on MI355X — round 10: Y never materialized. sg2y_k (block per
// node) builds 16-edge Y chunks in LDS via MFMA, scores+softmax+aggregates
// in-block; y3 gone; NS=4 (G2 33.5MB fills T). Rest = round 9 (proven).

#define NSd 8192
#define NNd 16384
#define NEd 131072

typedef unsigned short u16;
typedef unsigned int   u32;
typedef short bf16x8 __attribute__((ext_vector_type(8)));
typedef float f32x4  __attribute__((ext_vector_type(4)));

__device__ __forceinline__ float bf2f(u16 u){ return __uint_as_float(((u32)u) << 16); }
__device__ __forceinline__ u16 f2bf(float f){
  u32 u = __float_as_uint(f);
  u += 0x7fffu + ((u >> 16) & 1u);
  return (u16)(u >> 16);
}
__device__ __forceinline__ float eluf(float x){ return x > 0.f ? x : expm1f(x); }
__device__ __forceinline__ float leaky(float x){ return x > 0.f ? x : 0.2f * x; }
__device__ __forceinline__ float ldin(const void* p, size_t i, int fl){
  return fl ? bf2f(((const u16*)p)[i]) : ((const float*)p)[i];
}
__device__ __forceinline__ void lse_merge(float& m, float& z, float om, float oz){
  float M = fmaxf(m, om);
  z = z * __expf(m - M) + oz * __expf(om - M);
  m = M;
}

// ------------------------- workspace layout (bytes) -------------------------
static constexpr size_t OFF_WF   = 0;
static constexpr size_t OFF_CB   = 1529600;
static constexpr size_t OFF_U    = 1584896;      // 131072*64 bf16 (Ub)
static constexpr size_t OFF_W1B  = 18362112;     // W1T bf16
static constexpr size_t OFF_W2B  = 18427648;     // W2T bf16
static constexpr size_t OFF_AL1  = 35139328;     // 131072*8 f32 (by CSR pos)
static constexpr size_t OFF_SA   = 39333632;     // 131072*8 f32 (epos early | sg2y fallback)
static constexpr size_t OFF_HNA  = 43527936;     // 16384*512 f32
static constexpr size_t OFF_DEG  = 77082368;
static constexpr size_t OFF_RP   = 77147904;
static constexpr size_t OFF_FILL = 77213696;
static constexpr size_t OFF_CIDX = 77279232;
static constexpr size_t OFF_RBIG = 77803520;     // flash | G1b | HNB16+AN2
static constexpr size_t OFF_T    = 111357952;    // 32MB union
static constexpr size_t OFF_XCAT = 144912384;
static constexpr size_t OFF_FLAG = 144977920;
static constexpr size_t WS_NEED  = 144978176;

static constexpr size_t T_X1A = 0;
static constexpr size_t T_X2A = 2097152;
static constexpr size_t T_HN0 = 4194304;
static constexpr size_t T_AN1 = 8388608;
static constexpr size_t T_S   = 9437184;
static constexpr size_t T_G2  = 0;               // slice phase: 4096*8*512 bf16 = 33.5MB
static constexpr size_t R_PZ  = 16777216;        // pacc = 8*8192*64*4 below
static constexpr size_t R_AN2 = 17301504;

static constexpr int WO_PROJ = 0,      WO_W1 = 16384;
static constexpr int WO_AL1 = 49152,   WO_AR1 = 49664,  WO_AE1 = 50176;
static constexpr int WO_W2  = 50688;
static constexpr int WO_AL2 = 312832,  WO_AR2 = 313344, WO_AE2 = 313856;
static constexpr int WO_B1G = 314368,  WO_B1B = 315392;
static constexpr int WO_F1W = 316416,  WO_F1B = 381952;
static constexpr int WO_B2G = 382016,  WO_B2B = 382080;
static constexpr int WO_F2W = 382144,  WO_F2B = 382336;
static constexpr int WO_END = 382339;

static constexpr int CB_WC1 = 0;
static constexpr int CB_WE1 = 1024;
static constexpr int CB_WC2 = 1536;   // rows 0..7 = W2*(al2-ae2)
static constexpr int CB_WE2 = 9728;
static constexpr int CB_END = 13824;

// ------------------------------- dtype detect -------------------------------
__global__ __launch_bounds__(256) void detect_k(const u16* __restrict__ p, int* __restrict__ flag){
  __shared__ int bad;
  if (threadIdx.x == 0) bad = 0;
  __syncthreads();
  int b = 0;
  for (int i = threadIdx.x; i < 1024; i += 256){
    float f = bf2f(p[i]);
    if (!(fabsf(f) <= 100.f)) b++;
  }
  atomicAdd(&bad, b);
  __syncthreads();
  if (threadIdx.x == 0) *flag = (bad == 0) ? 1 : 0;
}

struct P17 { const void* p[17]; };

__global__ __launch_bounds__(256) void convw_k(P17 ps, float* __restrict__ wf, const int* __restrict__ flagp){
  const int i = blockIdx.x * 256 + threadIdx.x;
  if (i >= WO_END) return;
  const int fl = *flagp;
  const int ends[17] = {16384,49152,49664,50176,50688,312832,313344,313856,314368,
                        315392,316416,381952,382016,382080,382144,382336,382339};
  int seg = 0;
  while (i >= ends[seg]) seg++;
  const int start = seg ? ends[seg-1] : 0;
  wf[i] = ldin(ps.p[seg], i - start, fl);
}

__global__ __launch_bounds__(256) void convwT_k(const float* __restrict__ wf, u16* __restrict__ w1t,
                                                u16* __restrict__ w2t){
  const int i = blockIdx.x * 256 + threadIdx.x;
  if (i < 32768){
    const int c = i >> 6, k = i & 63;
    w1t[i] = f2bf(wf[WO_W1 + k * 512 + c]);
  } else if (i < 32768 + 262144){
    const int j = i - 32768;
    const int c = j >> 9, k = j & 511;
    w2t[j] = f2bf(wf[WO_W2 + k * 512 + c]);
  }
}

__global__ __launch_bounds__(256) void combos_k(const float* __restrict__ wf, float* __restrict__ cb){
  const int i = blockIdx.x * 256 + threadIdx.x;
  if (i >= CB_END) return;
  float acc = 0.f;
  if (i < 1024){
    const int o = i >> 6, d = i & 63, h = o & 7;
    const float* a = wf + ((o >> 3) ? WO_AR1 : WO_AL1) + h * 64;
    for (int dp = 0; dp < 64; dp++) acc += wf[WO_W1 + d * 512 + h * 64 + dp] * a[dp];
    cb[CB_WC1 + i] = acc;
  } else if (i < 1536){
    const int j = i - 1024, h = j >> 6, d = j & 63;
    for (int dp = 0; dp < 64; dp++) acc += wf[WO_W1 + d * 512 + h * 64 + dp] * wf[WO_AE1 + h * 64 + dp];
    cb[CB_WE1 + j] = acc;
  } else if (i < 9728){
    const int j = i - 1536, o = j >> 9, c = j & 511, h = o & 7;
    for (int dp = 0; dp < 64; dp++){
      const float av = (o >> 3) ? wf[WO_AR2 + h * 64 + dp]
                                : (wf[WO_AL2 + h * 64 + dp] - wf[WO_AE2 + h * 64 + dp]);
      acc += wf[WO_W2 + c * 512 + h * 64 + dp] * av;
    }
    cb[CB_WC2 + j] = acc;
  } else {
    const int j = i - 9728, h = j >> 9, c = j & 511;
    for (int dp = 0; dp < 64; dp++) acc += wf[WO_W2 + c * 512 + h * 64 + dp] * wf[WO_AE2 + h * 64 + dp];
    cb[CB_WE2 + j] = acc;
  }
}

// --------------------------- flash alignment (MFMA) -------------------------
__global__ __launch_bounds__(256) void flash_mfma_k(const void* __restrict__ Qp, const void* __restrict__ Kp,
                                                    const int* __restrict__ flagp, float* __restrict__ pacc,
                                                    float* __restrict__ pz){
  const int fl = *flagp;
  __shared__ __align__(16) u16 Qs[64][72];
  __shared__ __align__(16) u16 Ks[64][72];
  __shared__ __align__(16) u16 Kt[64][72];
  __shared__ __align__(16) u16 Ps[64][72];
  const int t = threadIdx.x;
  const int w = t >> 6;
  const int lane = t & 63;
  const int col = lane & 15;
  const int quad = lane >> 4;
  const int q0 = blockIdx.x * 64;
  const int kbeg = blockIdx.y * 1024;
  const int r = t >> 2, c0 = (t & 3) * 16;
  const int r2 = t & 31, cg = t >> 5;
  {
    if (fl){
      const uint4* qp = (const uint4*)((const u16*)Qp + (size_t)(q0 + r) * 64 + c0);
      *(uint4*)&Qs[r][c0] = qp[0];
      *(uint4*)&Qs[r][c0 + 8] = qp[1];
    } else {
      const float* qp = (const float*)Qp + (size_t)(q0 + r) * 64 + c0;
      for (int c = 0; c < 16; c++) Qs[r][c0 + c] = f2bf(qp[c]);
    }
  }
  f32x4 accO[4];
  #pragma unroll
  for (int d = 0; d < 4; d++) accO[d] = (f32x4){0.f, 0.f, 0.f, 0.f};
  float l_[4] = {0.f, 0.f, 0.f, 0.f};

  for (int kt = 0; kt < 1024; kt += 64){
    __syncthreads();
    if (fl){
      const uint4* kp = (const uint4*)((const u16*)Kp + (size_t)(kbeg + kt + r) * 64 + c0);
      *(uint4*)&Ks[r][c0] = kp[0];
      *(uint4*)&Ks[r][c0 + 8] = kp[1];
    } else {
      const float* kp = (const float*)Kp + (size_t)(kbeg + kt + r) * 64 + c0;
      for (int c = 0; c < 16; c++) Ks[r][c0 + c] = f2bf(kp[c]);
    }
    {
      u16 ra[8], rb[8];
      if (fl){
        const u16* k0 = (const u16*)Kp + (size_t)(kbeg + kt + 2*r2) * 64 + cg*8;
        *(uint4*)ra = *(const uint4*)k0;
        *(uint4*)rb = *(const uint4*)(k0 + 64);
      } else {
        const float* k0 = (const float*)Kp + (size_t)(kbeg + kt + 2*r2) * 64 + cg*8;
        for (int c = 0; c < 8; c++){ ra[c] = f2bf(k0[c]); rb[c] = f2bf(k0[64 + c]); }
      }
      #pragma unroll
      for (int c = 0; c < 8; c++)
        *(u32*)&Kt[cg*8 + c][2*r2] = (u32)ra[c] | ((u32)rb[c] << 16);
    }
    __syncthreads();
    f32x4 accS[4];
    #pragma unroll
    for (int nt = 0; nt < 4; nt++) accS[nt] = (f32x4){0.f, 0.f, 0.f, 0.f};
    #pragma unroll
    for (int ks = 0; ks < 2; ks++){
      bf16x8 a = *(const bf16x8*)&Qs[w*16 + col][ks*32 + quad*8];
      #pragma unroll
      for (int nt = 0; nt < 4; nt++){
        bf16x8 b = *(const bf16x8*)&Ks[nt*16 + col][ks*32 + quad*8];
        accS[nt] = __builtin_amdgcn_mfma_f32_16x16x32_bf16(a, b, accS[nt], 0, 0, 0);
      }
    }
    #pragma unroll
    for (int i = 0; i < 4; i++){
      float p0 = __expf(accS[0][i] - 32.f), p1 = __expf(accS[1][i] - 32.f);
      float p2 = __expf(accS[2][i] - 32.f), p3 = __expf(accS[3][i] - 32.f);
      float rs = p0 + p1 + p2 + p3;
      rs += __shfl_xor(rs, 1); rs += __shfl_xor(rs, 2); rs += __shfl_xor(rs, 4); rs += __shfl_xor(rs, 8);
      l_[i] += rs;
      Ps[w*16 + quad*4 + i][ 0 + col] = f2bf(p0);
      Ps[w*16 + quad*4 + i][16 + col] = f2bf(p1);
      Ps[w*16 + quad*4 + i][32 + col] = f2bf(p2);
      Ps[w*16 + quad*4 + i][48 + col] = f2bf(p3);
    }
    #pragma unroll
    for (int ks = 0; ks < 2; ks++){
      bf16x8 a = *(const bf16x8*)&Ps[w*16 + col][ks*32 + quad*8];
      #pragma unroll
      for (int d = 0; d < 4; d++){
        bf16x8 b = *(const bf16x8*)&Kt[d*16 + col][ks*32 + quad*8];
        accO[d] = __builtin_amdgcn_mfma_f32_16x16x32_bf16(a, b, accO[d], 0, 0, 0);
      }
    }
  }
  #pragma unroll
  for (int i = 0; i < 4; i++){
    const int row = q0 + w*16 + quad*4 + i;
    #pragma unroll
    for (int d = 0; d < 4; d++)
      pacc[((size_t)blockIdx.y * NSd + row) * 64 + d*16 + col] = accO[d][i];
    if (col == 0) pz[blockIdx.y * NSd + row] = l_[i];
  }
}

__global__ __launch_bounds__(256) void flash_merge_k(const float* __restrict__ pacc,
                                                     const float* __restrict__ pz, float* __restrict__ outp){
  const int t = threadIdx.x;
  const int r = blockIdx.x * 4 + (t >> 6);
  const int d = t & 63;
  float Zt = 0.f, v = 0.f;
  #pragma unroll
  for (int s = 0; s < 8; s++){
    Zt += pz[s * NSd + r];
    v  += pacc[((size_t)s * NSd + r) * 64 + d];
  }
  outp[(size_t)r * 64 + d] = v / Zt;
}

// ------------------------------- projection ---------------------------------
__global__ __launch_bounds__(256) void proj_k(const void* __restrict__ nbd1, const void* __restrict__ nbd2,
                                              const float* __restrict__ x1a, const float* __restrict__ x2a,
                                              const float* __restrict__ wf, float* __restrict__ hn0,
                                              const int* __restrict__ flagp){
  const int fl = *flagp;
  __shared__ float At[64][65], Bt[64][65];
  const int t = threadIdx.x, tx = t & 15, ty = t >> 4;
  const int m0 = blockIdx.x * 64;
  float acc[4][4] = {{0.f}};
  for (int kt = 0; kt < 256; kt += 64){
    __syncthreads();
    {
      const int i = t >> 2, c0 = (t & 3) * 16;
      const int mrow = m0 + i;
      const int side = mrow < NSd;
      const int mr = side ? mrow : mrow - NSd;
      const void* nb = side ? nbd1 : nbd2;
      const float* xa = side ? x1a : x2a;
      const int seg = kt >> 6;
      for (int c = 0; c < 16; c++){
        const int kk = c0 + c;
        const float nv = ldin(nb, (size_t)mr * 64 + kk, fl);
        const float av = xa[(size_t)mr * 64 + kk];
        At[i][kk] = (seg == 0) ? nv : (seg == 1) ? av : (seg == 2) ? (nv - av) : (nv * av);
      }
      const int kk = t >> 2;
      for (int c = 0; c < 16; c++) Bt[kk][c0 + c] = wf[WO_PROJ + (kt + kk) * 64 + c0 + c];
    }
    __syncthreads();
    #pragma unroll
    for (int k = 0; k < 64; k++){
      float a0 = At[ty*4+0][k], a1 = At[ty*4+1][k], a2 = At[ty*4+2][k], a3 = At[ty*4+3][k];
      float b0 = Bt[k][tx*4+0], b1 = Bt[k][tx*4+1], b2 = Bt[k][tx*4+2], b3 = Bt[k][tx*4+3];
      acc[0][0] = fmaf(a0,b0,acc[0][0]); acc[0][1] = fmaf(a0,b1,acc[0][1]); acc[0][2] = fmaf(a0,b2,acc[0][2]); acc[0][3] = fmaf(a0,b3,acc[0][3]);
      acc[1][0] = fmaf(a1,b0,acc[1][0]); acc[1][1] = fmaf(a1,b1,acc[1][1]); acc[1][2] = fmaf(a1,b2,acc[1][2]); acc[1][3] = fmaf(a1,b3,acc[1][3]);
      acc[2][0] = fmaf(a2,b0,acc[2][0]); acc[2][1] = fmaf(a2,b1,acc[2][1]); acc[2][2] = fmaf(a2,b2,acc[2][2]); acc[2][3] = fmaf(a2,b3,acc[2][3]);
      acc[3][0] = fmaf(a3,b0,acc[3][0]); acc[3][1] = fmaf(a3,b1,acc[3][1]); acc[3][2] = fmaf(a3,b2,acc[3][2]); acc[3][3] = fmaf(a3,b3,acc[3][3]);
    }
  }
  #pragma unroll
  for (int i = 0; i < 4; i++)
    #pragma unroll
    for (int j = 0; j < 4; j++)
      hn0[(size_t)(m0 + ty*4 + i) * 64 + tx*4 + j] = fmaxf(acc[i][j], 0.f);
}

// ---------------------- per-node combos -------------------------------------
__global__ __launch_bounds__(256) void an64_k(const float* __restrict__ hn0, const float* __restrict__ wc,
                                              float* __restrict__ an){
  const int id = blockIdx.x * 256 + threadIdx.x;
  const int n = id >> 4, o = id & 15;
  const float* row = hn0 + (size_t)n * 64;
  const float* wp = wc + o * 64;
  float acc = 0.f;
  for (int k = 0; k < 64; k += 4){
    const float4 r4 = *(const float4*)(row + k);
    const float4 w4 = *(const float4*)(wp + k);
    acc += r4.x*w4.x + r4.y*w4.y + r4.z*w4.z + r4.w*w4.w;
  }
  an[id] = acc;
}

__global__ __launch_bounds__(256) void anw_k(const float* __restrict__ HNA, const float* __restrict__ wc,
                                             float* __restrict__ an){
  __shared__ float W[16][516];
  const int t = threadIdx.x;
  for (int i = t; i < 8192; i += 256) W[i >> 9][i & 511] = wc[i];
  __syncthreads();
  const int node = blockIdx.x * 64 + (t >> 2);
  const int cb0 = (t & 3) * 4;
  const float* row = HNA + (size_t)node * 512;
  float acc[4] = {0.f, 0.f, 0.f, 0.f};
  for (int k = 0; k < 512; k += 4){
    const float4 r = *(const float4*)(row + k);
    #pragma unroll
    for (int j = 0; j < 4; j++){
      const float* wr = &W[cb0 + j][k];
      acc[j] += r.x * wr[0] + r.y * wr[1] + r.z * wr[2] + r.w * wr[3];
    }
  }
  #pragma unroll
  for (int j = 0; j < 4; j++) an[node * 16 + cb0 + j] = acc[j];
}

// -------------------- fused U build + layer-1 scores (by CSR pos) -----------
__global__ __launch_bounds__(256) void us1_k(const void* __restrict__ ebd, const float* __restrict__ hn0,
                                             const int* __restrict__ src, const int* __restrict__ dst,
                                             const float* __restrict__ cb, const float* __restrict__ an,
                                             const int* __restrict__ epos,
                                             u16* __restrict__ Ub, float* __restrict__ S,
                                             const int* __restrict__ flagp){
  __shared__ float we[512];
  const int t = threadIdx.x;
  for (int i = t; i < 512; i += 256) we[i] = cb[CB_WE1 + i];
  __syncthreads();
  const int fl = *flagp;
  const int id = blockIdx.x * 256 + t;
  const int e = id >> 4, q = id & 15, d0 = q * 4;
  const int sn = src[e];
  float ev[4];
  if (fl){
    const uint2 u = *(const uint2*)((const u16*)ebd + (size_t)e * 64 + d0);
    ev[0] = bf2f((u16)(u.x & 0xffffu)); ev[1] = bf2f((u16)(u.x >> 16));
    ev[2] = bf2f((u16)(u.y & 0xffffu)); ev[3] = bf2f((u16)(u.y >> 16));
  } else {
    const float4 f = *(const float4*)((const float*)ebd + (size_t)e * 64 + d0);
    ev[0] = f.x; ev[1] = f.y; ev[2] = f.z; ev[3] = f.w;
  }
  const float4 hv = *(const float4*)(hn0 + (size_t)sn * 64 + d0);
  ushort4 o;
  o.x = f2bf(ev[0] + hv.x); o.y = f2bf(ev[1] + hv.y);
  o.z = f2bf(ev[2] + hv.z); o.w = f2bf(ev[3] + hv.w);
  *(ushort4*)(Ub + (size_t)e * 64 + d0) = o;
  float p[8];
  #pragma unroll
  for (int h = 0; h < 8; h++){
    const float* wp = we + h * 64 + d0;
    p[h] = ev[0]*wp[0] + ev[1]*wp[1] + ev[2]*wp[2] + ev[3]*wp[3];
  }
  #pragma unroll
  for (int h = 0; h < 8; h++){
    p[h] += __shfl_xor(p[h], 1); p[h] += __shfl_xor(p[h], 2);
    p[h] += __shfl_xor(p[h], 4); p[h] += __shfl_xor(p[h], 8);
  }
  if (q == 0){
    const int dn = dst[e];
    const size_t pos = epos[e];
    #pragma unroll
    for (int h = 0; h < 8; h++)
      S[pos * 8 + h] = leaky(an[sn * 16 + h] + p[h] + an[dn * 16 + 8 + h]);
  }
}

__global__ __launch_bounds__(256) void segalpha_pos_k(const float* __restrict__ S, const int* __restrict__ rp,
                                                      float* __restrict__ AL){
  const int w = blockIdx.x * 4 + (threadIdx.x >> 6);
  const int lane = threadIdx.x & 63;
  const int n = w >> 3, h = w & 7;
  const int beg = rp[n], end = rp[n + 1];
  float m = -1e30f, z = 0.f;
  for (int base = beg; base < end; base += 64){
    const int idx = base + lane;
    float v = -1e30f, cc = 0.f;
    if (idx < end){ v = S[(size_t)idx * 8 + h]; cc = 1.f; }
    lse_merge(m, z, v, cc);
  }
  #pragma unroll
  for (int off = 32; off; off >>= 1){
    float om = __shfl_xor(m, off), oz = __shfl_xor(z, off);
    lse_merge(m, z, om, oz);
  }
  const float rz = 1.f / fmaxf(z, 1e-9f);
  for (int base = beg; base < end; base += 64){
    const int idx = base + lane;
    if (idx < end)
      AL[(size_t)idx * 8 + h] = __expf(S[(size_t)idx * 8 + h] - m) * rz;
  }
}

__global__ __launch_bounds__(256) void g1b_k(const float* __restrict__ AL, const u16* __restrict__ Ub,
                                             const int* __restrict__ rp, const int* __restrict__ cidx,
                                             u16* __restrict__ G1b){
  const int n = blockIdx.x;
  const int t = threadIdx.x;
  const int d = t & 63, hh = t >> 6;
  const int beg = rp[n], end = rp[n + 1];
  float a0 = 0.f, a1 = 0.f;
  for (int idx = beg; idx < end; idx++){
    const int e = cidx[idx];
    const float uv = bf2f(Ub[(size_t)e * 64 + d]);
    a0 = fmaf(AL[(size_t)idx * 8 + hh],     uv, a0);
    a1 = fmaf(AL[(size_t)idx * 8 + hh + 4], uv, a1);
  }
  G1b[(size_t)(n * 8 + hh)     * 64 + d] = f2bf(a0);
  G1b[(size_t)(n * 8 + hh + 4) * 64 + d] = f2bf(a1);
}

__global__ __launch_bounds__(256) void nft1m_k(const u16* __restrict__ G1b, const u16* __restrict__ W1T,
                                               float* __restrict__ HNA){
  const int t = threadIdx.x;
  const int w = t >> 6, lane = t & 63;
  const int col = lane & 15, quad = lane >> 4;
  const int h = blockIdx.y;
  const int nl0 = blockIdx.x * 32;
  const int mt = (w & 1) * 16;
  const int nb = (w >> 1) * 2;
  const u16* arow = G1b + ((size_t)(nl0 + mt + col) * 8 + h) * 64;
  const bf16x8 a0 = *(const bf16x8*)(arow + quad*8);
  const bf16x8 a1 = *(const bf16x8*)(arow + 32 + quad*8);
  #pragma unroll
  for (int nn = 0; nn < 2; nn++){
    const int nt = nb + nn;
    const u16* brow = W1T + (size_t)(h*64 + nt*16 + col) * 64;
    const bf16x8 b0 = *(const bf16x8*)(brow + quad*8);
    const bf16x8 b1 = *(const bf16x8*)(brow + 32 + quad*8);
    f32x4 acc = (f32x4){0.f, 0.f, 0.f, 0.f};
    acc = __builtin_amdgcn_mfma_f32_16x16x32_bf16(a0, b0, acc, 0, 0, 0);
    acc = __builtin_amdgcn_mfma_f32_16x16x32_bf16(a1, b1, acc, 0, 0, 0);
    #pragma unroll
    for (int i = 0; i < 4; i++)
      HNA[(size_t)(nl0 + mt + quad*4 + i) * 512 + h*64 + nt*16 + col] = eluf(acc[i]);
  }
}

// --------- build a 16-edge chunk of Y rows in LDS (MFMA, bf16) --------------
__device__ __forceinline__ void build_chunk(
    const u16* __restrict__ Ub, const float* __restrict__ AL1, const float* __restrict__ HNA,
    const u16* __restrict__ W1T, const int* __restrict__ src, const int* __restrict__ cidx,
    const int beg, const int c0, const int cnt, const int t,
    u16 (*Usc)[72], u16 (*Yl)[520], float (*als)[8], int* Es, int* Ssrc)
{
  if (t < 16){
    const int e = cidx[beg + ((t < cnt) ? (c0 + t) : 0)];
    Es[t] = e; Ssrc[t] = src[e];
  }
  if (t < 128){
    const int i = t >> 3, h8 = t & 7;
    als[i][h8] = (i < cnt) ? AL1[(size_t)(beg + c0 + i) * 8 + h8] : 0.f;
  }
  __syncthreads();
  if (t < 128){
    const int r = t >> 3, seg = (t & 7) * 8;
    *(ushort4*)&Usc[r][seg]     = *(const ushort4*)(Ub + (size_t)Es[r] * 64 + seg);
    *(ushort4*)&Usc[r][seg + 4] = *(const ushort4*)(Ub + (size_t)Es[r] * 64 + seg + 4);
  }
  __syncthreads();
  const int w = t >> 6, lane = t & 63, col = lane & 15, quad = lane >> 4;
  const bf16x8 a0 = *(const bf16x8*)&Usc[col][quad*8];
  const bf16x8 a1 = *(const bf16x8*)&Usc[col][32 + quad*8];
  #pragma unroll
  for (int hh = 0; hh < 2; hh++){
    const int h = w*2 + hh;
    #pragma unroll
    for (int nt = 0; nt < 4; nt++){
      const u16* brow = W1T + (size_t)(h*64 + nt*16 + col) * 64;
      const bf16x8 b0 = *(const bf16x8*)(brow + quad*8);
      const bf16x8 b1 = *(const bf16x8*)(brow + 32 + quad*8);
      f32x4 acc = (f32x4){0.f, 0.f, 0.f, 0.f};
      acc = __builtin_amdgcn_mfma_f32_16x16x32_bf16(a0, b0, acc, 0, 0, 0);
      acc = __builtin_amdgcn_mfma_f32_16x16x32_bf16(a1, b1, acc, 0, 0, 0);
      #pragma unroll
      for (int i = 0; i < 4; i++){
        const int row = quad*4 + i;
        if (row < cnt){
          const float v = eluf(als[row][h] * acc[i]) + HNA[(size_t)Ssrc[row]*512 + h*64 + nt*16 + col];
          Yl[row][h*64 + nt*16 + col] = f2bf(v);
        }
      }
    }
  }
  __syncthreads();
}

// fused layer-2: Y chunks in LDS -> scores -> softmax -> aggregation. 1 node/block.
__global__ __launch_bounds__(256) void sg2y_k(const u16* __restrict__ Ub, const float* __restrict__ AL1,
                                              const float* __restrict__ HNA, const u16* __restrict__ W1T,
                                              const float* __restrict__ cb, const float* __restrict__ AN2,
                                              const int* __restrict__ src, const int* __restrict__ cidx,
                                              const int* __restrict__ rp, float* __restrict__ SA,
                                              u16* __restrict__ G2, const int s){
  __shared__ float Wt2[8][512];
  __shared__ __align__(16) u16 Usc[16][72];
  __shared__ __align__(16) u16 Yl[16][520];
  __shared__ float sc[64][8];
  __shared__ float als[16][8];
  __shared__ int Es[16], Ssrc[16];
  __shared__ float mh[8], rzh[8];
  const int t = threadIdx.x;
  const int nl = blockIdx.x;
  const int n = s * 4096 + nl;
  const int beg = rp[n], end = rp[n + 1], m = end - beg;
  const bool small = (m <= 64);
  for (int idx = t; idx < 4096; idx += 256)
    Wt2[idx >> 9][idx & 511] = cb[CB_WE2 + idx];
  // PASS A: chunks -> Y in LDS -> scores
  for (int c0 = 0; c0 < m; c0 += 16){
    const int cnt = min(16, m - c0);
    __syncthreads();
    build_chunk(Ub, AL1, HNA, W1T, src, cidx, beg, c0, cnt, t, Usc, Yl, als, Es, Ssrc);
    {
      const int i = t >> 4, l16 = t & 15;
      float accs[8] = {0.f,0.f,0.f,0.f,0.f,0.f,0.f,0.f};
      if (i < cnt){
        for (int j = 0; j < 16; j++){
          const int c = l16*2 + j*32;
          const u32 yv = *(const u32*)&Yl[i][c];
          const float y0 = bf2f((u16)(yv & 0xffffu)), y1 = bf2f((u16)(yv >> 16));
          #pragma unroll
          for (int h2 = 0; h2 < 8; h2++)
            accs[h2] += y0 * Wt2[h2][c] + y1 * Wt2[h2][c + 1];
        }
      }
      #pragma unroll
      for (int h2 = 0; h2 < 8; h2++){
        float v = accs[h2];
        v += __shfl_xor(v, 1); v += __shfl_xor(v, 2);
        v += __shfl_xor(v, 4); v += __shfl_xor(v, 8);
        accs[h2] = v;
      }
      if (l16 == 0 && i < cnt){
        const int se = Ssrc[i];
        #pragma unroll
        for (int h2 = 0; h2 < 8; h2++){
          const float v = leaky(AN2[se * 16 + h2] + accs[h2] + AN2[n * 16 + 8 + h2]);
          if (small) sc[c0 + i][h2] = v;
          else       SA[(size_t)(beg + c0 + i) * 8 + h2] = v;
        }
      }
    }
  }
  __syncthreads();
  // softmax stats per h
  {
    const int h = t >> 5, l32 = t & 31;
    float mm = -1e30f, zz = 0.f;
    for (int i = l32; i < m; i += 32){
      const float v = small ? sc[i][h] : SA[(size_t)(beg + i) * 8 + h];
      lse_merge(mm, zz, v, 1.f);
    }
    #pragma unroll
    for (int off = 1; off < 32; off <<= 1){
      const float om = __shfl_xor(mm, off), oz = __shfl_xor(zz, off);
      lse_merge(mm, zz, om, oz);
    }
    if (l32 == 0){ mh[h] = mm; rzh[h] = 1.f / fmaxf(zz, 1e-9f); }
  }
  __syncthreads();
  if (small){
    for (int idx = t; idx < m * 8; idx += 256){
      const int i = idx >> 3, h = idx & 7;
      sc[i][h] = __expf(sc[i][h] - mh[h]) * rzh[h];
    }
    __syncthreads();
  }
  // PASS B: aggregation (Yl valid if m<=16; else rebuild per chunk)
  const int d0 = t * 2;
  float ac[8][2] = {{0.f}};
  for (int c0 = 0; c0 < m; c0 += 16){
    const int cnt = min(16, m - c0);
    if (m > 16){
      __syncthreads();
      build_chunk(Ub, AL1, HNA, W1T, src, cidx, beg, c0, cnt, t, Usc, Yl, als, Es, Ssrc);
    }
    for (int i = 0; i < cnt; i++){
      const u32 yv = *(const u32*)&Yl[i][d0];
      const float y0 = bf2f((u16)(yv & 0xffffu)), y1 = bf2f((u16)(yv >> 16));
      float al[8];
      if (small){
        #pragma unroll
        for (int h = 0; h < 8; h++) al[h] = sc[c0 + i][h];
      } else {
        #pragma unroll
        for (int h = 0; h < 8; h++)
          al[h] = __expf(SA[(size_t)(beg + c0 + i) * 8 + h] - mh[h]) * rzh[h];
      }
      #pragma unroll
      for (int h = 0; h < 8; h++){
        ac[h][0] = fmaf(al[h], y0, ac[h][0]);
        ac[h][1] = fmaf(al[h], y1, ac[h][1]);
      }
    }
  }
  #pragma unroll
  for (int h = 0; h < 8; h++){
    const u32 o = (u32)f2bf(ac[h][0]) | ((u32)f2bf(ac[h][1]) << 16);
    *(u32*)(G2 + ((size_t)nl * 8 + h) * 512 + d0) = o;
  }
}

// nft2 MFMA (NS=4: 4096 nodes/slice)
__global__ __launch_bounds__(256) void nft2m_k(const u16* __restrict__ G2, const u16* __restrict__ W2T,
                                               u16* __restrict__ HNB, const int s){
  const int t = threadIdx.x;
  const int w = t >> 6, lane = t & 63;
  const int col = lane & 15, quad = lane >> 4;
  const int h = blockIdx.y;
  const int nl0 = blockIdx.x * 32;
  const int mt = (w & 1) * 16;
  const int nb = (w >> 1) * 2;
  const u16* arow = G2 + ((size_t)((nl0 + mt + col) * 8) + h) * 512;
  #pragma unroll
  for (int nn = 0; nn < 2; nn++){
    const int nt = nb + nn;
    const u16* brow = W2T + (size_t)(h*64 + nt*16 + col) * 512;
    f32x4 acc = (f32x4){0.f, 0.f, 0.f, 0.f};
    #pragma unroll
    for (int ks = 0; ks < 16; ks++){
      const bf16x8 a = *(const bf16x8*)(arow + ks*32 + quad*8);
      const bf16x8 b = *(const bf16x8*)(brow + ks*32 + quad*8);
      acc = __builtin_amdgcn_mfma_f32_16x16x32_bf16(a, b, acc, 0, 0, 0);
    }
    #pragma unroll
    for (int i = 0; i < 4; i++)
      HNB[(size_t)(s*4096 + nl0 + mt + quad*4 + i) * 512 + h*64 + nt*16 + col] = f2bf(eluf(acc[i]));
  }
}

// ---------------------------------- CSR -------------------------------------
__global__ __launch_bounds__(256) void hist_k(const int* __restrict__ dst, int* __restrict__ deg){
  const int e = blockIdx.x * 256 + threadIdx.x;
  if (e < NEd) atomicAdd(&deg[dst[e]], 1);
}
__global__ __launch_bounds__(256) void scan_k(const int* __restrict__ deg, int* __restrict__ rp,
                                              int* __restrict__ fill){
  __shared__ int ps[257];
  const int t = threadIdx.x;
  const int base = t * 64;
  int s = 0;
  for (int i = 0; i < 64; i++) s += deg[base + i];
  ps[t + 1] = s;
  if (t == 0) ps[0] = 0;
  __syncthreads();
  if (t == 0) for (int i = 1; i <= 256; i++) ps[i] += ps[i - 1];
  __syncthreads();
  int off = ps[t];
  for (int i = 0; i < 64; i++){ rp[base + i] = off; fill[base + i] = off; off += deg[base + i]; }
  if (t == 255) rp[NNd] = off;
}
__global__ __launch_bounds__(256) void scatter_k(const int* __restrict__ dst, int* __restrict__ fill,
                                                 int* __restrict__ cidx, int* __restrict__ epos){
  const int e = blockIdx.x * 256 + threadIdx.x;
  if (e < NEd){
    int pos = atomicAdd(&fill[dst[e]], 1);
    cidx[pos] = e;
    epos[e] = pos;
  }
}

// ------------------------------- readout ------------------------------------
__global__ __launch_bounds__(256) void mean_k(const u16* __restrict__ HNB, float* __restrict__ xcat){
  const int sg = blockIdx.x;
  const int t = threadIdx.x;
  const int g = (sg < 16) ? sg : sg - 16;
  const int half = (sg < 16) ? 0 : 1;
  const int c0 = t * 2;
  float s0 = 0.f, s1 = 0.f;
  const u16* base = HNB + (size_t)sg * 512 * 512;
  for (int n = 0; n < 512; n++){
    const u32 u = *(const u32*)(base + (size_t)n * 512 + c0);
    s0 += bf2f((u16)(u & 0xffffu));
    s1 += bf2f((u16)(u >> 16));
  }
  xcat[g * 1024 + half * 512 + c0]     = s0 * (1.f / 512.f);
  xcat[g * 1024 + half * 512 + c0 + 1] = s1 * (1.f / 512.f);
}

__global__ __launch_bounds__(1024) void head_k(float* __restrict__ xcat, const float* __restrict__ wf,
                                               void* __restrict__ outp, const int* __restrict__ flagp){
  __shared__ float y1[16][64];
  __shared__ float y2[16][64];
  __shared__ float mu2s[64], sc2s[64];
  const int t = threadIdx.x;
  {
    float mu = 0.f;
    #pragma unroll
    for (int g = 0; g < 16; g++) mu += xcat[g * 1024 + t];
    mu *= (1.f / 16.f);
    float var = 0.f;
    #pragma unroll
    for (int g = 0; g < 16; g++){ float d = xcat[g * 1024 + t] - mu; var += d * d; }
    var *= (1.f / 16.f);
    const float sc = rsqrtf(var + 1e-5f) * wf[WO_B1G + t];
    const float sh = wf[WO_B1B + t] - mu * sc;
    #pragma unroll
    for (int g = 0; g < 16; g++) xcat[g * 1024 + t] = xcat[g * 1024 + t] * sc + sh;
  }
  __syncthreads();
  {
    const int gg = t >> 6, c = t & 63;
    float acc = wf[WO_F1B + c];
    for (int k = 0; k < 1024; k++) acc = fmaf(xcat[gg * 1024 + k], wf[WO_F1W + k * 64 + c], acc);
    y1[gg][c] = fmaxf(acc, 0.f);
  }
  __syncthreads();
  if (t < 64){
    float mu = 0.f;
    #pragma unroll
    for (int g = 0; g < 16; g++) mu += y1[g][t];
    mu *= (1.f / 16.f);
    float var = 0.f;
    #pragma unroll
    for (int g = 0; g < 16; g++){ float d = y1[g][t] - mu; var += d * d; }
    var *= (1.f / 16.f);
    mu2s[t] = mu; sc2s[t] = rsqrtf(var + 1e-5f) * wf[WO_B2G + t];
  }
  __syncthreads();
  {
    const int gg = t >> 6, c = t & 63;
    y2[gg][c] = (y1[gg][c] - mu2s[c]) * sc2s[c] + wf[WO_B2B + c];
  }
  __syncthreads();
  if (t < 48){
    const int gg = t / 3, c = t % 3;
    float acc = wf[WO_F2B + c];
    #pragma unroll
    for (int k = 0; k < 64; k++) acc = fmaf(y2[gg][k], wf[WO_F2W + k * 3 + c], acc);
    if (*flagp) ((u16*)outp)[t] = f2bf(acc);
    else        ((float*)outp)[t] = acc;
  }
}

// --------------------------------- launch -----------------------------------
extern "C" void kernel_launch(void* const* d_in, const int* in_sizes, int n_in,
                              void* d_out, int out_size, void* d_ws, size_t ws_size,
                              hipStream_t stream) {
  (void)in_sizes; (void)n_in; (void)out_size;
  if (ws_size < WS_NEED) return;

  const int* src = (const int*)d_in[3];
  const int* dst = (const int*)d_in[4];
  char* w = (char*)d_ws;

  float* wf   = (float*)(w + OFF_WF);
  float* cb   = (float*)(w + OFF_CB);
  u16*   Ub   = (u16*)(w + OFF_U);
  u16*   W1T  = (u16*)(w + OFF_W1B);
  u16*   W2T  = (u16*)(w + OFF_W2B);
  float* AL1  = (float*)(w + OFF_AL1);
  float* SA   = (float*)(w + OFF_SA);
  int*   epos = (int*)(w + OFF_SA);
  float* HNA  = (float*)(w + OFF_HNA);
  int*   deg  = (int*)(w + OFF_DEG);
  int*   rp   = (int*)(w + OFF_RP);
  int*   fill = (int*)(w + OFF_FILL);
  int*   cidx = (int*)(w + OFF_CIDX);
  float* rbig = (float*)(w + OFF_RBIG);
  float* xcat = (float*)(w + OFF_XCAT);
  int*   flag = (int*)(w + OFF_FLAG);

  float* x1a  = (float*)(w + OFF_T + T_X1A);
  float* x2a  = (float*)(w + OFF_T + T_X2A);
  float* hn0  = (float*)(w + OFF_T + T_HN0);
  float* AN1  = (float*)(w + OFF_T + T_AN1);
  float* S    = (float*)(w + OFF_T + T_S);
  u16*   G2   = (u16*)(w + OFF_T + T_G2);

  float* pacc = rbig;
  float* pz   = (float*)(w + OFF_RBIG + R_PZ);
  u16*   G1b  = (u16*)(w + OFF_RBIG);
  u16*   HNB  = (u16*)(w + OFF_RBIG);
  float* AN2  = (float*)(w + OFF_RBIG + R_AN2);

  // 0. detect + weights + combos
  detect_k<<<1, 256, 0, stream>>>((const u16*)d_in[0], flag);
  P17 ps;
  for (int i = 0; i < 17; i++) ps.p[i] = d_in[6 + i];
  convw_k<<<(WO_END + 255) / 256, 256, 0, stream>>>(ps, wf, flag);
  convwT_k<<<(32768 + 262144 + 255) / 256, 256, 0, stream>>>(wf, W1T, W2T);
  combos_k<<<(CB_END + 255) / 256, 256, 0, stream>>>(wf, cb);

  // 1. CSR over dst (+ epos)
  hipMemsetAsync(deg, 0, NNd * sizeof(int), stream);
  hist_k<<<NEd / 256, 256, 0, stream>>>(dst, deg);
  scan_k<<<1, 256, 0, stream>>>(deg, rp, fill);
  scatter_k<<<NEd / 256, 256, 0, stream>>>(dst, fill, cidx, epos);

  // 2. alignment (MFMA flash, 8 key-splits, no-max softmax)
  flash_mfma_k<<<dim3(128, 8), 256, 0, stream>>>(d_in[0], d_in[1], flag, pacc, pz);
  flash_merge_k<<<NSd / 4, 256, 0, stream>>>(pacc, pz, x1a);
  flash_mfma_k<<<dim3(128, 8), 256, 0, stream>>>(d_in[1], d_in[0], flag, pacc, pz);
  flash_merge_k<<<NSd / 4, 256, 0, stream>>>(pacc, pz, x2a);

  // 3. projection
  proj_k<<<NNd / 64, 256, 0, stream>>>(d_in[0], d_in[1], x1a, x2a, wf, hn0, flag);

  // 4. GAT layer 1
  an64_k<<<NNd * 16 / 256, 256, 0, stream>>>(hn0, cb + CB_WC1, AN1);
  us1_k<<<NEd * 16 / 256, 256, 0, stream>>>(d_in[2], hn0, src, dst, cb, AN1, epos, Ub, S, flag);
  segalpha_pos_k<<<NNd * 8 / 4, 256, 0, stream>>>(S, rp, AL1);
  g1b_k<<<NNd, 256, 0, stream>>>(AL1, Ub, rp, cidx, G1b);
  nft1m_k<<<dim3(NNd / 32, 8), 256, 0, stream>>>(G1b, W1T, HNA);

  // 5. layer-2 per-node combos
  anw_k<<<NNd / 64, 256, 0, stream>>>(HNA, cb + CB_WC2, AN2);

  // 6. layer-2: 4 slices × (sg2y, nft2m) — Y never materialized
  for (int s = 0; s < 4; s++){
    sg2y_k<<<4096, 256, 0, stream>>>(Ub, AL1, HNA, W1T, cb, AN2, src, cidx, rp, SA, G2, s);
    nft2m_k<<<dim3(128, 8), 256, 0, stream>>>(G2, W2T, HNB, s);
  }

  // 7. readout
  mean_k<<<32, 256, 0, stream>>>(HNB, xcat);
  head_k<<<1, 1024, 0, stream>>>(xcat, wf, d_out, flag);
}